// Round 13
// baseline (256.205 us; speedup 1.0000x reference)
//
#include <hip/hip_runtime.h>
#include <stdint.h>

typedef unsigned short u16;
typedef unsigned int u32;
typedef __bf16 bf16x8 __attribute__((ext_vector_type(8)));
typedef float f32x4 __attribute__((ext_vector_type(4)));

#define LDT 72
#define HLD 516

// ---------- bf16 helpers ----------
__device__ __forceinline__ float bf2f(u16 u) {
  u32 v = ((u32)u) << 16;
  return __builtin_bit_cast(float, v);
}
__device__ __forceinline__ u16 f2bf(float f) {
  u32 u = __builtin_bit_cast(u32, f);
  u32 r = u + 0x7fffu + ((u >> 16) & 1u);
  return (u16)(r >> 16);
}

__device__ __forceinline__ float block_sum4(float v, float* red, int t) {
#pragma unroll
  for (int o = 32; o; o >>= 1) v += __shfl_xor(v, o, 64);
  if ((t & 63) == 0) red[t >> 6] = v;
  __syncthreads();
  float r = red[0] + red[1] + red[2] + red[3];
  __syncthreads();
  return r;
}

// ---- kernel 1: blocks [0,1024) convert Wv fp32->bf16; rest do LN1 rows -----
__global__ __launch_bounds__(256) void cvt_ln(
    const float* __restrict__ WV, u16* __restrict__ WVD,
    const float* __restrict__ X, const float* __restrict__ G,
    const float* __restrict__ Bt, u16* __restrict__ O) {
  int t = threadIdx.x;
  if (blockIdx.x < 1024) {
    int i = blockIdx.x * 1024 + t * 4;
    float4 f = *(const float4*)(WV + i);
    u32 lo = (u32)f2bf(f.x) | ((u32)f2bf(f.y) << 16);
    u32 hi = (u32)f2bf(f.z) | ((u32)f2bf(f.w) << 16);
    uint2 val = {lo, hi};
    *(uint2*)(WVD + i) = val;
    return;
  }
  __shared__ float red[4];
  int row = blockIdx.x - 1024;
  float4 xv = *(const float4*)(X + (size_t)row * 1024 + t * 4);
  float v[4] = {xv.x, xv.y, xv.z, xv.w};
  float s = v[0] + v[1] + v[2] + v[3];
  s = block_sum4(s, red, t);
  float mean = s * (1.f / 1024.f);
  float q = 0.f;
#pragma unroll
  for (int i = 0; i < 4; ++i) { float d = v[i] - mean; q += d * d; }
  q = block_sum4(q, red, t);
  float rstd = rsqrtf(q * (1.f / 1024.f) + 1e-5f);
  float4 g = *(const float4*)(G + t * 4);
  float4 b = *(const float4*)(Bt + t * 4);
  float gg[4] = {g.x, g.y, g.z, g.w}, bb[4] = {b.x, b.y, b.z, b.w};
  u16 o[4];
#pragma unroll
  for (int i = 0; i < 4; ++i) o[i] = f2bf((v[i] - mean) * rstd * gg[i] + bb[i]);
  u32* op = (u32*)(O + (size_t)row * 1024 + t * 4);
  op[0] = (u32)o[0] | ((u32)o[1] << 16);
  op[1] = (u32)o[2] | ((u32)o[3] << 16);
}

// ---- kernel 2: [0,296) = 128x128 v-GEMM (padded-LDS explicit staging);
// ----           [296,424) = q_fused --------------------------------------
__global__ __launch_bounds__(256) void vgemm_q(
    const u16* __restrict__ A, const u16* __restrict__ W,
    const float* __restrict__ bias, u16* __restrict__ C, int M,
    const float* __restrict__ WQ, const float* __restrict__ QB,
    const float* __restrict__ WK, const float* __restrict__ BK,
    u16* __restrict__ QW, float* __restrict__ C0) {
  int t = threadIdx.x;
  if (blockIdx.x < 296) {
    __shared__ u16 As[128 * LDT];   // padded: row stride 72 u16 (144 B)
    __shared__ u16 Bs[128 * LDT];
    int lane = t & 63, wv = t >> 6;
    int bm = (blockIdx.x % 37) * 128, bn = (blockIdx.x / 37) * 128;
    int quad = lane >> 4, rlow = lane & 15;
    int wrow = (wv & 1) * 64, wcol = (wv >> 1) * 64;
    int srow = t >> 3;          // 0..31
    int scol = (t & 7) * 8;     // 0..56 step 8
    f32x4 acc[4][4] = {};
    for (int k0 = 0; k0 < 1024; k0 += 64) {
      __syncthreads();
#pragma unroll
      for (int rr = 0; rr < 4; ++rr) {
        int row = srow + rr * 32;
        int gm = bm + row;
        uint4 da = {0, 0, 0, 0};
        if (gm < M) da = *(const uint4*)(A + (size_t)gm * 1024 + k0 + scol);
        *(uint4*)(&As[row * LDT + scol]) = da;
        int gn = bn + row;  // N=1024 exact
        uint4 dw = *(const uint4*)(W + (size_t)gn * 1024 + k0 + scol);
        *(uint4*)(&Bs[row * LDT + scol]) = dw;
      }
      __syncthreads();
#pragma unroll
      for (int kk = 0; kk < 64; kk += 32) {
        bf16x8 a[4], b[4];
#pragma unroll
        for (int i = 0; i < 4; ++i)
          a[i] = *(const bf16x8*)(&As[(wrow + i * 16 + rlow) * LDT + kk + quad * 8]);
#pragma unroll
        for (int j = 0; j < 4; ++j)
          b[j] = *(const bf16x8*)(&Bs[(wcol + j * 16 + rlow) * LDT + kk + quad * 8]);
#pragma unroll
        for (int i = 0; i < 4; ++i)
#pragma unroll
          for (int j = 0; j < 4; ++j)
            acc[i][j] = __builtin_amdgcn_mfma_f32_16x16x32_bf16(a[i], b[j], acc[i][j], 0, 0, 0);
      }
    }
#pragma unroll
    for (int j = 0; j < 4; ++j) {
      int gn = bn + wcol + j * 16 + rlow;
      float bv = bias[gn];
#pragma unroll
      for (int i = 0; i < 4; ++i)
#pragma unroll
        for (int r = 0; r < 4; ++r) {
          int gm = bm + wrow + i * 16 + quad * 4 + r;
          if (gm < M) C[(size_t)gm * 1024 + gn] = f2bf(acc[i][j][r] + bv);
        }
    }
    return;
  }
  // ----- q_fused segment -----
  __shared__ float hsf[1024];
  __shared__ float ps[256];
  __shared__ float qs[64];
  int bh = blockIdx.x - 296, b = bh >> 4, h = bh & 15;
  {
    uint2 two = *(const uint2*)(A + (size_t)b * 1024 + t * 4);
    hsf[t * 4 + 0] = bf2f(two.x & 0xffff);
    hsf[t * 4 + 1] = bf2f(two.x >> 16);
    hsf[t * 4 + 2] = bf2f(two.y & 0xffff);
    hsf[t * 4 + 3] = bf2f(two.y >> 16);
  }
  __syncthreads();
  {
    int n = t >> 2, part = t & 3;
    const float* wr = WQ + (size_t)(h * 64 + n) * 1024 + part * 256;
    const float* hp = hsf + part * 256;
    float acc = 0.f;
#pragma unroll 4
    for (int d = 0; d < 256; d += 4) {
      float4 w = *(const float4*)(wr + d);
      acc += w.x * hp[d] + w.y * hp[d + 1] + w.z * hp[d + 2] + w.w * hp[d + 3];
    }
    ps[t] = acc;
  }
  __syncthreads();
  if (t < 64) {
    float q = ps[t * 4] + ps[t * 4 + 1] + ps[t * 4 + 2] + ps[t * 4 + 3] + QB[h * 64 + t];
    qs[t] = q * 0.125f;
  }
  __syncthreads();
  float a4[4] = {0.f, 0.f, 0.f, 0.f};
  int d0 = t * 4;
#pragma unroll 4
  for (int n2 = 0; n2 < 64; ++n2) {
    float4 w = *(const float4*)(WK + (size_t)(h * 64 + n2) * 1024 + d0);
    float q = qs[n2];
    a4[0] += q * w.x; a4[1] += q * w.y; a4[2] += q * w.z; a4[3] += q * w.w;
  }
  u16 o[4];
#pragma unroll
  for (int i = 0; i < 4; ++i) o[i] = f2bf(a4[i]);
  u32* op = (u32*)(QW + (size_t)bh * 1024 + d0);
  op[0] = (u32)o[0] | ((u32)o[1] << 16);
  op[1] = (u32)o[2] | ((u32)o[3] << 16);
  if (t == 0) {
    float c = 0.f;
    for (int n2 = 0; n2 < 64; ++n2) c += qs[n2] * BK[h * 64 + n2];
    C0[bh] = c;
  }
}

// ---- split-K partials, W in fp32 (converted during staging) ----------------
__global__ __launch_bounds__(256) void gemm_bt_splitk_p(
    const u16* __restrict__ A, int lda, const float* __restrict__ Wf, int ldw,
    float* __restrict__ P, int pstride, int ldc, int M, int N, int KC) {
  __shared__ u16 As[64 * LDT];
  __shared__ u16 Bs[64 * LDT];
  int t = threadIdx.x;
  int bm = blockIdx.x * 64, bn = blockIdx.y * 64;
  int kbase = blockIdx.z * KC;
  float* PZ = P + (size_t)blockIdx.z * pstride;
  int lane = t & 63, wv = t >> 6;
  f32x4 acc[4] = {};
  int srow = t >> 3, scol = (t & 7) * 8;

  for (int k0 = kbase; k0 < kbase + KC; k0 += 64) {
    __syncthreads();
#pragma unroll
    for (int rr = 0; rr < 2; ++rr) {
      int r = srow + rr * 32;
      int gm = bm + r;
      uint4 da = {0, 0, 0, 0};
      if (gm < M) da = *(const uint4*)(A + (size_t)gm * lda + k0 + scol);
      *(uint4*)(&As[r * LDT + scol]) = da;
      int gn = bn + r;
      uint4 dw = {0, 0, 0, 0};
      if (gn < N) {
        const float* wr = Wf + (size_t)gn * ldw + k0 + scol;
        float4 w0 = *(const float4*)(wr);
        float4 w1 = *(const float4*)(wr + 4);
        dw.x = (u32)f2bf(w0.x) | ((u32)f2bf(w0.y) << 16);
        dw.y = (u32)f2bf(w0.z) | ((u32)f2bf(w0.w) << 16);
        dw.z = (u32)f2bf(w1.x) | ((u32)f2bf(w1.y) << 16);
        dw.w = (u32)f2bf(w1.z) | ((u32)f2bf(w1.w) << 16);
      }
      *(uint4*)(&Bs[r * LDT + scol]) = dw;
    }
    __syncthreads();
    int quad = lane >> 4, rlow = lane & 15;
#pragma unroll
    for (int kk = 0; kk < 64; kk += 32) {
      bf16x8 a = *(const bf16x8*)(&As[(wv * 16 + rlow) * LDT + kk + quad * 8]);
#pragma unroll
      for (int j = 0; j < 4; ++j) {
        bf16x8 b = *(const bf16x8*)(&Bs[(j * 16 + rlow) * LDT + kk + quad * 8]);
        acc[j] = __builtin_amdgcn_mfma_f32_16x16x32_bf16(a, b, acc[j], 0, 0, 0);
      }
    }
  }
  int quad = lane >> 4, cidx = lane & 15;
#pragma unroll
  for (int j = 0; j < 4; ++j) {
    int gn = bn + j * 16 + cidx;
#pragma unroll
    for (int r = 0; r < 4; ++r) {
      int gm = bm + wv * 16 + quad * 4 + r;
      if (gm < M && gn < N) PZ[(size_t)gm * ldc + gn] = acc[j][r];
    }
  }
}

// ---- reduce 8 out-proj partials(+bias) + x0 residual + LN2 ------------------
__global__ __launch_bounds__(256) void resid_ln_red(
    const float* __restrict__ X, const float* __restrict__ OP,
    const float* __restrict__ OB, const float* __restrict__ G,
    const float* __restrict__ Bt, float* __restrict__ CLS, u16* __restrict__ H2) {
  __shared__ float red[4];
  const int PS = 136 * 1024;
  int row = blockIdx.x, t = threadIdx.x;
  int bi = (row < 128) ? (row >> 4) : (row - 128);
  float4 xv = *(const float4*)(X + (size_t)bi * 1024 + t * 4);
  float4 ob = *(const float4*)(OB + t * 4);
  float v[4] = {xv.x + ob.x, xv.y + ob.y, xv.z + ob.z, xv.w + ob.w};
#pragma unroll
  for (int z = 0; z < 8; ++z) {
    float4 pv = *(const float4*)(OP + (size_t)z * PS + (size_t)row * 1024 + t * 4);
    v[0] += pv.x; v[1] += pv.y; v[2] += pv.z; v[3] += pv.w;
  }
  float* cp = CLS + (size_t)row * 1024 + t * 4;
#pragma unroll
  for (int i = 0; i < 4; ++i) cp[i] = v[i];
  float s = v[0] + v[1] + v[2] + v[3];
  s = block_sum4(s, red, t);
  float mean = s * (1.f / 1024.f);
  float q = 0.f;
#pragma unroll
  for (int i = 0; i < 4; ++i) { float d = v[i] - mean; q += d * d; }
  q = block_sum4(q, red, t);
  float rstd = rsqrtf(q * (1.f / 1024.f) + 1e-5f);
  float4 g = *(const float4*)(G + t * 4);
  float4 b = *(const float4*)(Bt + t * 4);
  float gg[4] = {g.x, g.y, g.z, g.w}, bb[4] = {b.x, b.y, b.z, b.w};
  u16 o[4];
#pragma unroll
  for (int i = 0; i < 4; ++i) o[i] = f2bf((v[i] - mean) * rstd * gg[i] + bb[i]);
  u32* op = (u32*)(H2 + (size_t)row * 1024 + t * 4);
  op[0] = (u32)o[0] | ((u32)o[1] << 16);
  op[1] = (u32)o[2] | ((u32)o[3] << 16);
}

// ---- reduce 4 fc partials + bias, QuickGELU -> bf16 ------------------------
__global__ __launch_bounds__(256) void gelu_red(
    const float* __restrict__ FP, const float* __restrict__ FB,
    u16* __restrict__ O, int total) {
  const int PS = 136 * 4096;
  int i = (blockIdx.x * 256 + threadIdx.x) * 4;
  if (i < total) {
#pragma unroll
    for (int k = 0; k < 4; ++k) {
      int idx = i + k;
      float v = FB[idx & 4095];
#pragma unroll
      for (int z = 0; z < 4; ++z) v += FP[(size_t)z * PS + idx];
      O[idx] = f2bf(v / (1.f + __expf(-1.702f * v)));
    }
  }
}

// ---- reduce 16 proj partials + bias + clspre -> fp32 out -------------------
__global__ __launch_bounds__(256) void final_red(
    const float* __restrict__ PP, const float* __restrict__ PB,
    const float* __restrict__ CLS, float* __restrict__ O, int total) {
  const int PS = 136 * 1024;
  int i = (blockIdx.x * 256 + threadIdx.x) * 4;
  if (i < total) {
#pragma unroll
    for (int k = 0; k < 4; ++k) {
      int idx = i + k;
      float v = PB[idx & 1023] + CLS[idx];
#pragma unroll
      for (int z = 0; z < 16; ++z) v += PP[(size_t)z * PS + idx];
      O[idx] = v;
    }
  }
}

// ------ attn: h-tile AND qw rows staged in LDS; 4 independent accs ----------
__global__ __launch_bounds__(256) void attn_dot(
    const u16* __restrict__ H, const u16* __restrict__ QW,
    const float* __restrict__ C0, float* __restrict__ ATT) {
  __shared__ __align__(16) u32 Hs[16 * HLD];
  __shared__ __align__(16) u32 Qs[16 * HLD];
  int b = blockIdx.y, s0 = blockIdx.x * 16, t = threadIdx.x;
  for (int idx = t; idx < 16 * 512; idx += 256) {
    int row = idx >> 9, col = idx & 511;
    int s = s0 + row;
    u32 v = 0;
    if (s < 577) v = *(const u32*)(H + ((size_t)(s * 8 + b) << 10) + col * 2);
    Hs[row * HLD + col] = v;
    Qs[row * HLD + col] = *(const u32*)(QW + (size_t)(b * 16 + row) * 1024 + col * 2);
  }
  __syncthreads();
  int si = t & 15, hh = t >> 4;
  int s = s0 + si;
  if (s < 577) {
    const u32* hr = &Hs[si * HLD];
    const u32* qr = &Qs[hh * HLD];
    float a0 = 0.f, a1 = 0.f, a2 = 0.f, a3 = 0.f;
    for (int d = 0; d < 512; d += 8) {
      uint4 hv = *(const uint4*)(&hr[d]);
      uint4 qv = *(const uint4*)(&qr[d]);
      uint4 hw = *(const uint4*)(&hr[d + 4]);
      uint4 qw2 = *(const uint4*)(&qr[d + 4]);
      a0 += bf2f(hv.x & 0xffff) * bf2f(qv.x & 0xffff) + bf2f(hv.x >> 16) * bf2f(qv.x >> 16);
      a1 += bf2f(hv.y & 0xffff) * bf2f(qv.y & 0xffff) + bf2f(hv.y >> 16) * bf2f(qv.y >> 16);
      a2 += bf2f(hv.z & 0xffff) * bf2f(qv.z & 0xffff) + bf2f(hv.z >> 16) * bf2f(qv.z >> 16);
      a3 += bf2f(hv.w & 0xffff) * bf2f(qv.w & 0xffff) + bf2f(hv.w >> 16) * bf2f(qv.w >> 16);
      a0 += bf2f(hw.x & 0xffff) * bf2f(qw2.x & 0xffff) + bf2f(hw.x >> 16) * bf2f(qw2.x >> 16);
      a1 += bf2f(hw.y & 0xffff) * bf2f(qw2.y & 0xffff) + bf2f(hw.y >> 16) * bf2f(qw2.y >> 16);
      a2 += bf2f(hw.z & 0xffff) * bf2f(qw2.z & 0xffff) + bf2f(hw.z >> 16) * bf2f(qw2.z >> 16);
      a3 += bf2f(hw.w & 0xffff) * bf2f(qw2.w & 0xffff) + bf2f(hw.w >> 16) * bf2f(qw2.w >> 16);
    }
    ATT[(size_t)(b * 16 + hh) * 577 + s] = (a0 + a1) + (a2 + a3) + C0[b * 16 + hh];
  }
}

// ---- softmax(attn [+mask fp32]) then PV over bf16 V ------------------------
__global__ __launch_bounds__(256) void softmax_pv(
    const float* __restrict__ ATT, const float* __restrict__ MASK,
    const u16* __restrict__ V, u16* __restrict__ AO) {
  const int S = 577;
  int blk = blockIdx.x;
  int b = blk / 272, rem = blk % 272;
  int x = rem >> 4, h = rem & 15;
  __shared__ float p[S];
  __shared__ float redm[4];
  __shared__ float reds[4];
  __shared__ float partial[256];
  int t = threadIdx.x, lane = t & 63, wv = t >> 6;
  const float* arow = ATT + (size_t)(b * 16 + h) * S;
  float lmax = -3e38f;
  for (int s = t; s < S; s += 256) {
    float v = arow[s];
    if (x < 16) v += MASK[(size_t)((b * 16 + x) * 16 + h) * S + s];
    p[s] = v;
    lmax = fmaxf(lmax, v);
  }
#pragma unroll
  for (int o = 32; o; o >>= 1) lmax = fmaxf(lmax, __shfl_xor(lmax, o, 64));
  if (lane == 0) redm[wv] = lmax;
  __syncthreads();
  float m = fmaxf(fmaxf(redm[0], redm[1]), fmaxf(redm[2], redm[3]));
  float lsum = 0.f;
  for (int s = t; s < S; s += 256) {
    float e = __expf(p[s] - m);
    p[s] = e;
    lsum += e;
  }
#pragma unroll
  for (int o = 32; o; o >>= 1) lsum += __shfl_xor(lsum, o, 64);
  if (lane == 0) reds[wv] = lsum;
  __syncthreads();
  float inv = 1.f / (reds[0] + reds[1] + reds[2] + reds[3]);
  float acc = 0.f;
  const u16* vb = V + h * 64 + lane;
  int s = wv;
  for (; s + 28 < S; s += 32) {
    float w0 = p[s], w1 = p[s + 4], w2 = p[s + 8], w3 = p[s + 12];
    float w4 = p[s + 16], w5 = p[s + 20], w6 = p[s + 24], w7 = p[s + 28];
    float v0 = bf2f(vb[(size_t)((s)*8 + b) << 10]);
    float v1 = bf2f(vb[(size_t)((s + 4) * 8 + b) << 10]);
    float v2 = bf2f(vb[(size_t)((s + 8) * 8 + b) << 10]);
    float v3 = bf2f(vb[(size_t)((s + 12) * 8 + b) << 10]);
    float v4 = bf2f(vb[(size_t)((s + 16) * 8 + b) << 10]);
    float v5 = bf2f(vb[(size_t)((s + 20) * 8 + b) << 10]);
    float v6 = bf2f(vb[(size_t)((s + 24) * 8 + b) << 10]);
    float v7 = bf2f(vb[(size_t)((s + 28) * 8 + b) << 10]);
    acc += w0 * v0 + w1 * v1 + w2 * v2 + w3 * v3;
    acc += w4 * v4 + w5 * v5 + w6 * v6 + w7 * v7;
  }
  for (; s < S; s += 4) acc += p[s] * bf2f(vb[(size_t)(s * 8 + b) << 10]);
  partial[t] = acc;
  __syncthreads();
  if (t < 64) {
    float r = (partial[t] + partial[t + 64] + partial[t + 128] + partial[t + 192]) * inv;
    int row = (x < 16) ? (b * 16 + x) : (128 + b);
    AO[(size_t)row * 1024 + h * 64 + t] = f2bf(r);
  }
}

// ----------------------------------------------------------------------------
extern "C" void kernel_launch(void* const* d_in, const int* in_sizes, int n_in,
                              void* d_out, int out_size, void* d_ws, size_t ws_size,
                              hipStream_t stream) {
  const float* x      = (const float*)d_in[0];
  const float* mask   = (const float*)d_in[1];
  const float* in_w   = (const float*)d_in[5];
  const float* in_b   = (const float*)d_in[6];
  const float* out_w  = (const float*)d_in[7];
  const float* out_b  = (const float*)d_in[8];
  const float* ln1_g  = (const float*)d_in[9];
  const float* ln1_b  = (const float*)d_in[10];
  const float* ln2_g  = (const float*)d_in[11];
  const float* ln2_b  = (const float*)d_in[12];
  const float* fc_w   = (const float*)d_in[13];
  const float* fc_b   = (const float*)d_in[14];
  const float* proj_w = (const float*)d_in[15];
  const float* proj_b = (const float*)d_in[16];
  float* out = (float*)d_out;

  const int SB = 577 * 8;  // 4616
  char* base = (char*)d_ws;
  size_t off = 0;
  auto alloc = [&](size_t bytes) {
    char* p = base + off;
    off += (bytes + 255) & ~(size_t)255;
    return p;
  };
  u16* wv_b     = (u16*)alloc((size_t)1024 * 1024 * 2);
  u16* h        = (u16*)alloc((size_t)SB * 1024 * 2);
  u16* v        = (u16*)alloc((size_t)SB * 1024 * 2);
  u16* qw       = (u16*)alloc(128 * 1024 * 2);
  float* c0     = (float*)alloc(128 * 4);
  float* attn   = (float*)alloc(128 * 577 * 4);
  u16* attn_out = (u16*)alloc(136 * 1024 * 2);
  float* Op     = (float*)alloc((size_t)8 * 136 * 1024 * 4);
  float* clspre = (float*)alloc(136 * 1024 * 4);
  u16* h2       = (u16*)alloc(136 * 1024 * 2);
  float* Fp     = (float*)alloc((size_t)4 * 136 * 4096 * 4);
  u16* hg       = (u16*)alloc((size_t)136 * 4096 * 2);
  float* Pp     = (float*)alloc((size_t)16 * 136 * 1024 * 4);
  // ~46 MB used; ws_size ~268 MB (measured R7)

  // 1) wv cvt + LN1 fused
  cvt_ln<<<1024 + SB, 256, 0, stream>>>(in_w + (size_t)2048 * 1024, wv_b,
                                        x, ln1_g, ln1_b, h);
  // 2) v-GEMM (conflict-free padded LDS) + q_fused
  vgemm_q<<<296 + 128, 256, 0, stream>>>(
      h, wv_b, in_b + 2048, v, SB,
      in_w, in_b, in_w + (size_t)1024 * 1024, in_b + 1024, qw, c0);
  // 3) attn logits
  attn_dot<<<dim3(37, 8), 256, 0, stream>>>(h, qw, c0, attn);
  // 4) softmax(+mask) + PV
  softmax_pv<<<8 * 17 * 16, 256, 0, stream>>>(attn, mask, v, attn_out);
  // 5) out-proj partials (z=8, KC=128), fp32 W
  gemm_bt_splitk_p<<<dim3(3, 16, 8), 256, 0, stream>>>(
      attn_out, 1024, out_w, 1024, Op, 136 * 1024, 1024, 136, 1024, 128);
  // 6) reduce(8) + residual + LN2
  resid_ln_red<<<136, 256, 0, stream>>>(x, Op, out_b, ln2_g, ln2_b, clspre, h2);
  // 7) fc partials (z=4, KC=256), fp32 W; then reduce+bias+QuickGELU
  gemm_bt_splitk_p<<<dim3(3, 64, 4), 256, 0, stream>>>(
      h2, 1024, fc_w, 1024, Fp, 136 * 4096, 4096, 136, 4096, 256);
  gelu_red<<<544, 256, 0, stream>>>(Fp, fc_b, hg, 136 * 4096);
  // 8) proj partials (z=16, KC=256), fp32 W; then reduce+bias+clspre -> out
  gemm_bt_splitk_p<<<dim3(3, 16, 16), 256, 0, stream>>>(
      hg, 4096, proj_w, 4096, Pp, 136 * 1024, 1024, 136, 1024, 256);
  final_red<<<136, 256, 0, stream>>>(Pp, proj_b, clspre, out, 136 * 1024);

  (void)in_sizes; (void)n_in; (void)out_size; (void)ws_size;
}

// Round 14
// 243.668 us; speedup vs baseline: 1.0514x; 1.0514x over previous
//
#include <hip/hip_runtime.h>
#include <stdint.h>

typedef unsigned short u16;
typedef unsigned int u32;
typedef __bf16 bf16x8 __attribute__((ext_vector_type(8)));
typedef float f32x4 __attribute__((ext_vector_type(4)));

#define LDT 72
#define HLD 516

// ---------- bf16 helpers ----------
__device__ __forceinline__ float bf2f(u16 u) {
  u32 v = ((u32)u) << 16;
  return __builtin_bit_cast(float, v);
}
__device__ __forceinline__ u16 f2bf(float f) {
  u32 u = __builtin_bit_cast(u32, f);
  u32 r = u + 0x7fffu + ((u >> 16) & 1u);
  return (u16)(r >> 16);
}

__device__ __forceinline__ float block_sum4(float v, float* red, int t) {
#pragma unroll
  for (int o = 32; o; o >>= 1) v += __shfl_xor(v, o, 64);
  if ((t & 63) == 0) red[t >> 6] = v;
  __syncthreads();
  float r = red[0] + red[1] + red[2] + red[3];
  __syncthreads();
  return r;
}

// async global->LDS, 16B per lane
#define GLD16(gp, lp)                                                   \
  __builtin_amdgcn_global_load_lds(                                     \
      (const __attribute__((address_space(1))) void*)(gp),              \
      (__attribute__((address_space(3))) void*)(lp), 16, 0, 0)

// ---- kernel 1: blocks [0,1024) convert Wv fp32->bf16; rest do LN1 rows -----
__global__ __launch_bounds__(256) void cvt_ln(
    const float* __restrict__ WV, u16* __restrict__ WVD,
    const float* __restrict__ X, const float* __restrict__ G,
    const float* __restrict__ Bt, u16* __restrict__ O) {
  int t = threadIdx.x;
  if (blockIdx.x < 1024) {
    int i = blockIdx.x * 1024 + t * 4;
    float4 f = *(const float4*)(WV + i);
    u32 lo = (u32)f2bf(f.x) | ((u32)f2bf(f.y) << 16);
    u32 hi = (u32)f2bf(f.z) | ((u32)f2bf(f.w) << 16);
    uint2 val = {lo, hi};
    *(uint2*)(WVD + i) = val;
    return;
  }
  __shared__ float red[4];
  int row = blockIdx.x - 1024;
  float4 xv = *(const float4*)(X + (size_t)row * 1024 + t * 4);
  float v[4] = {xv.x, xv.y, xv.z, xv.w};
  float s = v[0] + v[1] + v[2] + v[3];
  s = block_sum4(s, red, t);
  float mean = s * (1.f / 1024.f);
  float q = 0.f;
#pragma unroll
  for (int i = 0; i < 4; ++i) { float d = v[i] - mean; q += d * d; }
  q = block_sum4(q, red, t);
  float rstd = rsqrtf(q * (1.f / 1024.f) + 1e-5f);
  float4 g = *(const float4*)(G + t * 4);
  float4 b = *(const float4*)(Bt + t * 4);
  float gg[4] = {g.x, g.y, g.z, g.w}, bb[4] = {b.x, b.y, b.z, b.w};
  u16 o[4];
#pragma unroll
  for (int i = 0; i < 4; ++i) o[i] = f2bf((v[i] - mean) * rstd * gg[i] + bb[i]);
  u32* op = (u32*)(O + (size_t)row * 1024 + t * 4);
  op[0] = (u32)o[0] | ((u32)o[1] << 16);
  op[1] = (u32)o[2] | ((u32)o[3] << 16);
}

// ---- kernel 2: [0,296) = 128x128 v-GEMM, GLD16 staging + XOR-swizzled LDS;
// ----           [296,424) = q_fused ----------------------------------------
__global__ __launch_bounds__(256) void vgemm_q(
    const u16* __restrict__ A, const u16* __restrict__ W,
    const float* __restrict__ bias, u16* __restrict__ C, int M,
    const float* __restrict__ WQ, const float* __restrict__ QB,
    const float* __restrict__ WK, const float* __restrict__ BK,
    u16* __restrict__ QW, float* __restrict__ C0) {
  int t = threadIdx.x;
  if (blockIdx.x < 296) {
    __shared__ u16 As[128 * 64];
    __shared__ u16 Bs[128 * 64];
    int lane = t & 63, wv = t >> 6;
    int bm = (blockIdx.x % 37) * 128, bn = (blockIdx.x / 37) * 128;
    int quad = lane >> 4, rlow = lane & 15;
    int lrow = lane >> 3;                    // 0..7 = row within 8-row block
    int lcol = (((lane & 7) ^ lrow) * 8);    // XOR-swizzled global chunk
    int wrow = (wv & 1) * 64, wcol = (wv >> 1) * 64;
    int rx = (rlow & 7) << 3;                // swizzle term for reads (u16)
    f32x4 acc[4][4] = {};
    for (int k0 = 0; k0 < 1024; k0 += 64) {
      __syncthreads();
#pragma unroll
      for (int j = 0; j < 4; ++j) {
        int rb = j * 4 + wv;                 // row-block 0..15, 8 rows each
        int row = rb * 8 + lrow;
        int gm = bm + row; if (gm >= M) gm = M - 1;  // clamp: dup, never stored
        GLD16(A + (size_t)gm * 1024 + k0 + lcol, &As[rb * 8 * 64]);
        int gn = bn + row;                   // N = 1024 exact
        GLD16(W + (size_t)gn * 1024 + k0 + lcol, &Bs[rb * 8 * 64]);
      }
      __syncthreads();
#pragma unroll
      for (int kk = 0; kk < 64; kk += 32) {
        // LDS chunk c holds global chunk c ^ (row&7); global chunk wanted
        // is cq = (kk>>3)+quad, so read chunk cq ^ (rlow&7).
        int coff = ((kk >> 3) + quad) << 3;  // cq*8 u16
        bf16x8 a[4], b[4];
#pragma unroll
        for (int i = 0; i < 4; ++i)
          a[i] = *(const bf16x8*)(&As[(wrow + i * 16 + rlow) * 64 + (coff ^ rx)]);
#pragma unroll
        for (int j = 0; j < 4; ++j)
          b[j] = *(const bf16x8*)(&Bs[(wcol + j * 16 + rlow) * 64 + (coff ^ rx)]);
#pragma unroll
        for (int i = 0; i < 4; ++i)
#pragma unroll
          for (int j = 0; j < 4; ++j)
            acc[i][j] = __builtin_amdgcn_mfma_f32_16x16x32_bf16(a[i], b[j], acc[i][j], 0, 0, 0);
      }
    }
#pragma unroll
    for (int j = 0; j < 4; ++j) {
      int gn = bn + wcol + j * 16 + rlow;
      float bv = bias[gn];
#pragma unroll
      for (int i = 0; i < 4; ++i)
#pragma unroll
        for (int r = 0; r < 4; ++r) {
          int gm = bm + wrow + i * 16 + quad * 4 + r;
          if (gm < M) C[(size_t)gm * 1024 + gn] = f2bf(acc[i][j][r] + bv);
        }
    }
    return;
  }
  // ----- q_fused segment -----
  __shared__ float hsf[1024];
  __shared__ float ps[256];
  __shared__ float qs[64];
  int bh = blockIdx.x - 296, b = bh >> 4, h = bh & 15;
  {
    uint2 two = *(const uint2*)(A + (size_t)b * 1024 + t * 4);
    hsf[t * 4 + 0] = bf2f(two.x & 0xffff);
    hsf[t * 4 + 1] = bf2f(two.x >> 16);
    hsf[t * 4 + 2] = bf2f(two.y & 0xffff);
    hsf[t * 4 + 3] = bf2f(two.y >> 16);
  }
  __syncthreads();
  {
    int n = t >> 2, part = t & 3;
    const float* wr = WQ + (size_t)(h * 64 + n) * 1024 + part * 256;
    const float* hp = hsf + part * 256;
    float acc = 0.f;
#pragma unroll 4
    for (int d = 0; d < 256; d += 4) {
      float4 w = *(const float4*)(wr + d);
      acc += w.x * hp[d] + w.y * hp[d + 1] + w.z * hp[d + 2] + w.w * hp[d + 3];
    }
    ps[t] = acc;
  }
  __syncthreads();
  if (t < 64) {
    float q = ps[t * 4] + ps[t * 4 + 1] + ps[t * 4 + 2] + ps[t * 4 + 3] + QB[h * 64 + t];
    qs[t] = q * 0.125f;
  }
  __syncthreads();
  float a4[4] = {0.f, 0.f, 0.f, 0.f};
  int d0 = t * 4;
#pragma unroll 4
  for (int n2 = 0; n2 < 64; ++n2) {
    float4 w = *(const float4*)(WK + (size_t)(h * 64 + n2) * 1024 + d0);
    float q = qs[n2];
    a4[0] += q * w.x; a4[1] += q * w.y; a4[2] += q * w.z; a4[3] += q * w.w;
  }
  u16 o[4];
#pragma unroll
  for (int i = 0; i < 4; ++i) o[i] = f2bf(a4[i]);
  u32* op = (u32*)(QW + (size_t)bh * 1024 + d0);
  op[0] = (u32)o[0] | ((u32)o[1] << 16);
  op[1] = (u32)o[2] | ((u32)o[3] << 16);
  if (t == 0) {
    float c = 0.f;
    for (int n2 = 0; n2 < 64; ++n2) c += qs[n2] * BK[h * 64 + n2];
    C0[bh] = c;
  }
}

// ---- split-K partials, W in fp32 (converted during staging) ----------------
__global__ __launch_bounds__(256) void gemm_bt_splitk_p(
    const u16* __restrict__ A, int lda, const float* __restrict__ Wf, int ldw,
    float* __restrict__ P, int pstride, int ldc, int M, int N, int KC) {
  __shared__ u16 As[64 * LDT];
  __shared__ u16 Bs[64 * LDT];
  int t = threadIdx.x;
  int bm = blockIdx.x * 64, bn = blockIdx.y * 64;
  int kbase = blockIdx.z * KC;
  float* PZ = P + (size_t)blockIdx.z * pstride;
  int lane = t & 63, wv = t >> 6;
  f32x4 acc[4] = {};
  int srow = t >> 3, scol = (t & 7) * 8;

  for (int k0 = kbase; k0 < kbase + KC; k0 += 64) {
    __syncthreads();
#pragma unroll
    for (int rr = 0; rr < 2; ++rr) {
      int r = srow + rr * 32;
      int gm = bm + r;
      uint4 da = {0, 0, 0, 0};
      if (gm < M) da = *(const uint4*)(A + (size_t)gm * lda + k0 + scol);
      *(uint4*)(&As[r * LDT + scol]) = da;
      int gn = bn + r;
      uint4 dw = {0, 0, 0, 0};
      if (gn < N) {
        const float* wr = Wf + (size_t)gn * ldw + k0 + scol;
        float4 w0 = *(const float4*)(wr);
        float4 w1 = *(const float4*)(wr + 4);
        dw.x = (u32)f2bf(w0.x) | ((u32)f2bf(w0.y) << 16);
        dw.y = (u32)f2bf(w0.z) | ((u32)f2bf(w0.w) << 16);
        dw.z = (u32)f2bf(w1.x) | ((u32)f2bf(w1.y) << 16);
        dw.w = (u32)f2bf(w1.z) | ((u32)f2bf(w1.w) << 16);
      }
      *(uint4*)(&Bs[r * LDT + scol]) = dw;
    }
    __syncthreads();
    int quad = lane >> 4, rlow = lane & 15;
#pragma unroll
    for (int kk = 0; kk < 64; kk += 32) {
      bf16x8 a = *(const bf16x8*)(&As[(wv * 16 + rlow) * LDT + kk + quad * 8]);
#pragma unroll
      for (int j = 0; j < 4; ++j) {
        bf16x8 b = *(const bf16x8*)(&Bs[(j * 16 + rlow) * LDT + kk + quad * 8]);
        acc[j] = __builtin_amdgcn_mfma_f32_16x16x32_bf16(a, b, acc[j], 0, 0, 0);
      }
    }
  }
  int quad = lane >> 4, cidx = lane & 15;
#pragma unroll
  for (int j = 0; j < 4; ++j) {
    int gn = bn + j * 16 + cidx;
#pragma unroll
    for (int r = 0; r < 4; ++r) {
      int gm = bm + wv * 16 + quad * 4 + r;
      if (gm < M && gn < N) PZ[(size_t)gm * ldc + gn] = acc[j][r];
    }
  }
}

// ---- reduce 8 out-proj partials(+bias) + x0 residual + LN2 ------------------
__global__ __launch_bounds__(256) void resid_ln_red(
    const float* __restrict__ X, const float* __restrict__ OP,
    const float* __restrict__ OB, const float* __restrict__ G,
    const float* __restrict__ Bt, float* __restrict__ CLS, u16* __restrict__ H2) {
  __shared__ float red[4];
  const int PS = 136 * 1024;
  int row = blockIdx.x, t = threadIdx.x;
  int bi = (row < 128) ? (row >> 4) : (row - 128);
  float4 xv = *(const float4*)(X + (size_t)bi * 1024 + t * 4);
  float4 ob = *(const float4*)(OB + t * 4);
  float v[4] = {xv.x + ob.x, xv.y + ob.y, xv.z + ob.z, xv.w + ob.w};
#pragma unroll
  for (int z = 0; z < 8; ++z) {
    float4 pv = *(const float4*)(OP + (size_t)z * PS + (size_t)row * 1024 + t * 4);
    v[0] += pv.x; v[1] += pv.y; v[2] += pv.z; v[3] += pv.w;
  }
  float* cp = CLS + (size_t)row * 1024 + t * 4;
#pragma unroll
  for (int i = 0; i < 4; ++i) cp[i] = v[i];
  float s = v[0] + v[1] + v[2] + v[3];
  s = block_sum4(s, red, t);
  float mean = s * (1.f / 1024.f);
  float q = 0.f;
#pragma unroll
  for (int i = 0; i < 4; ++i) { float d = v[i] - mean; q += d * d; }
  q = block_sum4(q, red, t);
  float rstd = rsqrtf(q * (1.f / 1024.f) + 1e-5f);
  float4 g = *(const float4*)(G + t * 4);
  float4 b = *(const float4*)(Bt + t * 4);
  float gg[4] = {g.x, g.y, g.z, g.w}, bb[4] = {b.x, b.y, b.z, b.w};
  u16 o[4];
#pragma unroll
  for (int i = 0; i < 4; ++i) o[i] = f2bf((v[i] - mean) * rstd * gg[i] + bb[i]);
  u32* op = (u32*)(H2 + (size_t)row * 1024 + t * 4);
  op[0] = (u32)o[0] | ((u32)o[1] << 16);
  op[1] = (u32)o[2] | ((u32)o[3] << 16);
}

// ---- reduce 4 fc partials + bias, QuickGELU -> bf16 ------------------------
__global__ __launch_bounds__(256) void gelu_red(
    const float* __restrict__ FP, const float* __restrict__ FB,
    u16* __restrict__ O, int total) {
  const int PS = 136 * 4096;
  int i = (blockIdx.x * 256 + threadIdx.x) * 4;
  if (i < total) {
#pragma unroll
    for (int k = 0; k < 4; ++k) {
      int idx = i + k;
      float v = FB[idx & 4095];
#pragma unroll
      for (int z = 0; z < 4; ++z) v += FP[(size_t)z * PS + idx];
      O[idx] = f2bf(v / (1.f + __expf(-1.702f * v)));
    }
  }
}

// ---- reduce 16 proj partials + bias + clspre -> fp32 out -------------------
__global__ __launch_bounds__(256) void final_red(
    const float* __restrict__ PP, const float* __restrict__ PB,
    const float* __restrict__ CLS, float* __restrict__ O, int total) {
  const int PS = 136 * 1024;
  int i = (blockIdx.x * 256 + threadIdx.x) * 4;
  if (i < total) {
#pragma unroll
    for (int k = 0; k < 4; ++k) {
      int idx = i + k;
      float v = PB[idx & 1023] + CLS[idx];
#pragma unroll
      for (int z = 0; z < 16; ++z) v += PP[(size_t)z * PS + idx];
      O[idx] = v;
    }
  }
}

// ------ attn: h-tile AND qw rows staged in LDS; 4 independent accs ----------
__global__ __launch_bounds__(256) void attn_dot(
    const u16* __restrict__ H, const u16* __restrict__ QW,
    const float* __restrict__ C0, float* __restrict__ ATT) {
  __shared__ __align__(16) u32 Hs[16 * HLD];
  __shared__ __align__(16) u32 Qs[16 * HLD];
  int b = blockIdx.y, s0 = blockIdx.x * 16, t = threadIdx.x;
  for (int idx = t; idx < 16 * 512; idx += 256) {
    int row = idx >> 9, col = idx & 511;
    int s = s0 + row;
    u32 v = 0;
    if (s < 577) v = *(const u32*)(H + ((size_t)(s * 8 + b) << 10) + col * 2);
    Hs[row * HLD + col] = v;
    Qs[row * HLD + col] = *(const u32*)(QW + (size_t)(b * 16 + row) * 1024 + col * 2);
  }
  __syncthreads();
  int si = t & 15, hh = t >> 4;
  int s = s0 + si;
  if (s < 577) {
    const u32* hr = &Hs[si * HLD];
    const u32* qr = &Qs[hh * HLD];
    float a0 = 0.f, a1 = 0.f, a2 = 0.f, a3 = 0.f;
    for (int d = 0; d < 512; d += 8) {
      uint4 hv = *(const uint4*)(&hr[d]);
      uint4 qv = *(const uint4*)(&qr[d]);
      uint4 hw = *(const uint4*)(&hr[d + 4]);
      uint4 qw2 = *(const uint4*)(&qr[d + 4]);
      a0 += bf2f(hv.x & 0xffff) * bf2f(qv.x & 0xffff) + bf2f(hv.x >> 16) * bf2f(qv.x >> 16);
      a1 += bf2f(hv.y & 0xffff) * bf2f(qv.y & 0xffff) + bf2f(hv.y >> 16) * bf2f(qv.y >> 16);
      a2 += bf2f(hv.z & 0xffff) * bf2f(qv.z & 0xffff) + bf2f(hv.z >> 16) * bf2f(qv.z >> 16);
      a3 += bf2f(hv.w & 0xffff) * bf2f(qv.w & 0xffff) + bf2f(hv.w >> 16) * bf2f(qv.w >> 16);
      a0 += bf2f(hw.x & 0xffff) * bf2f(qw2.x & 0xffff) + bf2f(hw.x >> 16) * bf2f(qw2.x >> 16);
      a1 += bf2f(hw.y & 0xffff) * bf2f(qw2.y & 0xffff) + bf2f(hw.y >> 16) * bf2f(qw2.y >> 16);
      a2 += bf2f(hw.z & 0xffff) * bf2f(qw2.z & 0xffff) + bf2f(hw.z >> 16) * bf2f(qw2.z >> 16);
      a3 += bf2f(hw.w & 0xffff) * bf2f(qw2.w & 0xffff) + bf2f(hw.w >> 16) * bf2f(qw2.w >> 16);
    }
    ATT[(size_t)(b * 16 + hh) * 577 + s] = (a0 + a1) + (a2 + a3) + C0[b * 16 + hh];
  }
}

// ---- softmax(attn [+mask fp32]) then PV over bf16 V ------------------------
__global__ __launch_bounds__(256) void softmax_pv(
    const float* __restrict__ ATT, const float* __restrict__ MASK,
    const u16* __restrict__ V, u16* __restrict__ AO) {
  const int S = 577;
  int blk = blockIdx.x;
  int b = blk / 272, rem = blk % 272;
  int x = rem >> 4, h = rem & 15;
  __shared__ float p[S];
  __shared__ float redm[4];
  __shared__ float reds[4];
  __shared__ float partial[256];
  int t = threadIdx.x, lane = t & 63, wv = t >> 6;
  const float* arow = ATT + (size_t)(b * 16 + h) * S;
  float lmax = -3e38f;
  for (int s = t; s < S; s += 256) {
    float v = arow[s];
    if (x < 16) v += MASK[(size_t)((b * 16 + x) * 16 + h) * S + s];
    p[s] = v;
    lmax = fmaxf(lmax, v);
  }
#pragma unroll
  for (int o = 32; o; o >>= 1) lmax = fmaxf(lmax, __shfl_xor(lmax, o, 64));
  if (lane == 0) redm[wv] = lmax;
  __syncthreads();
  float m = fmaxf(fmaxf(redm[0], redm[1]), fmaxf(redm[2], redm[3]));
  float lsum = 0.f;
  for (int s = t; s < S; s += 256) {
    float e = __expf(p[s] - m);
    p[s] = e;
    lsum += e;
  }
#pragma unroll
  for (int o = 32; o; o >>= 1) lsum += __shfl_xor(lsum, o, 64);
  if (lane == 0) reds[wv] = lsum;
  __syncthreads();
  float inv = 1.f / (reds[0] + reds[1] + reds[2] + reds[3]);
  float acc = 0.f;
  const u16* vb = V + h * 64 + lane;
  int s = wv;
  for (; s + 28 < S; s += 32) {
    float w0 = p[s], w1 = p[s + 4], w2 = p[s + 8], w3 = p[s + 12];
    float w4 = p[s + 16], w5 = p[s + 20], w6 = p[s + 24], w7 = p[s + 28];
    float v0 = bf2f(vb[(size_t)((s)*8 + b) << 10]);
    float v1 = bf2f(vb[(size_t)((s + 4) * 8 + b) << 10]);
    float v2 = bf2f(vb[(size_t)((s + 8) * 8 + b) << 10]);
    float v3 = bf2f(vb[(size_t)((s + 12) * 8 + b) << 10]);
    float v4 = bf2f(vb[(size_t)((s + 16) * 8 + b) << 10]);
    float v5 = bf2f(vb[(size_t)((s + 20) * 8 + b) << 10]);
    float v6 = bf2f(vb[(size_t)((s + 24) * 8 + b) << 10]);
    float v7 = bf2f(vb[(size_t)((s + 28) * 8 + b) << 10]);
    acc += w0 * v0 + w1 * v1 + w2 * v2 + w3 * v3;
    acc += w4 * v4 + w5 * v5 + w6 * v6 + w7 * v7;
  }
  for (; s < S; s += 4) acc += p[s] * bf2f(vb[(size_t)(s * 8 + b) << 10]);
  partial[t] = acc;
  __syncthreads();
  if (t < 64) {
    float r = (partial[t] + partial[t + 64] + partial[t + 128] + partial[t + 192]) * inv;
    int row = (x < 16) ? (b * 16 + x) : (128 + b);
    AO[(size_t)row * 1024 + h * 64 + t] = f2bf(r);
  }
}

// ----------------------------------------------------------------------------
extern "C" void kernel_launch(void* const* d_in, const int* in_sizes, int n_in,
                              void* d_out, int out_size, void* d_ws, size_t ws_size,
                              hipStream_t stream) {
  const float* x      = (const float*)d_in[0];
  const float* mask   = (const float*)d_in[1];
  const float* in_w   = (const float*)d_in[5];
  const float* in_b   = (const float*)d_in[6];
  const float* out_w  = (const float*)d_in[7];
  const float* out_b  = (const float*)d_in[8];
  const float* ln1_g  = (const float*)d_in[9];
  const float* ln1_b  = (const float*)d_in[10];
  const float* ln2_g  = (const float*)d_in[11];
  const float* ln2_b  = (const float*)d_in[12];
  const float* fc_w   = (const float*)d_in[13];
  const float* fc_b   = (const float*)d_in[14];
  const float* proj_w = (const float*)d_in[15];
  const float* proj_b = (const float*)d_in[16];
  float* out = (float*)d_out;

  const int SB = 577 * 8;  // 4616
  char* base = (char*)d_ws;
  size_t off = 0;
  auto alloc = [&](size_t bytes) {
    char* p = base + off;
    off += (bytes + 255) & ~(size_t)255;
    return p;
  };
  u16* wv_b     = (u16*)alloc((size_t)1024 * 1024 * 2);
  u16* h        = (u16*)alloc((size_t)SB * 1024 * 2);
  u16* v        = (u16*)alloc((size_t)SB * 1024 * 2);
  u16* qw       = (u16*)alloc(128 * 1024 * 2);
  float* c0     = (float*)alloc(128 * 4);
  float* attn   = (float*)alloc(128 * 577 * 4);
  u16* attn_out = (u16*)alloc(136 * 1024 * 2);
  float* Op     = (float*)alloc((size_t)8 * 136 * 1024 * 4);
  float* clspre = (float*)alloc(136 * 1024 * 4);
  u16* h2       = (u16*)alloc(136 * 1024 * 2);
  float* Fp     = (float*)alloc((size_t)4 * 136 * 4096 * 4);
  u16* hg       = (u16*)alloc((size_t)136 * 4096 * 2);
  float* Pp     = (float*)alloc((size_t)16 * 136 * 1024 * 4);
  // ~46 MB used; ws_size ~268 MB (measured R7)

  // 1) wv cvt + LN1 fused
  cvt_ln<<<1024 + SB, 256, 0, stream>>>(in_w + (size_t)2048 * 1024, wv_b,
                                        x, ln1_g, ln1_b, h);
  // 2) v-GEMM (GLD16 + XOR-swizzled LDS reads) + q_fused
  vgemm_q<<<296 + 128, 256, 0, stream>>>(
      h, wv_b, in_b + 2048, v, SB,
      in_w, in_b, in_w + (size_t)1024 * 1024, in_b + 1024, qw, c0);
  // 3) attn logits
  attn_dot<<<dim3(37, 8), 256, 0, stream>>>(h, qw, c0, attn);
  // 4) softmax(+mask) + PV
  softmax_pv<<<8 * 17 * 16, 256, 0, stream>>>(attn, mask, v, attn_out);
  // 5) out-proj partials (z=8, KC=128), fp32 W
  gemm_bt_splitk_p<<<dim3(3, 16, 8), 256, 0, stream>>>(
      attn_out, 1024, out_w, 1024, Op, 136 * 1024, 1024, 136, 1024, 128);
  // 6) reduce(8) + residual + LN2
  resid_ln_red<<<136, 256, 0, stream>>>(x, Op, out_b, ln2_g, ln2_b, clspre, h2);
  // 7) fc partials (z=4, KC=256), fp32 W; then reduce+bias+QuickGELU
  gemm_bt_splitk_p<<<dim3(3, 64, 4), 256, 0, stream>>>(
      h2, 1024, fc_w, 1024, Fp, 136 * 4096, 4096, 136, 4096, 256);
  gelu_red<<<544, 256, 0, stream>>>(Fp, fc_b, hg, 136 * 4096);
  // 8) proj partials (z=16, KC=256), fp32 W; then reduce+bias+clspre -> out
  gemm_bt_splitk_p<<<dim3(3, 16, 16), 256, 0, stream>>>(
      hg, 4096, proj_w, 4096, Pp, 136 * 1024, 1024, 136, 1024, 256);
  final_red<<<136, 256, 0, stream>>>(Pp, proj_b, clspre, out, 136 * 1024);

  (void)in_sizes; (void)n_in; (void)out_size; (void)ws_size;
}

// Round 15
// 236.355 us; speedup vs baseline: 1.0840x; 1.0309x over previous
//
#include <hip/hip_runtime.h>
#include <stdint.h>

typedef unsigned short u16;
typedef unsigned int u32;
typedef __bf16 bf16x8 __attribute__((ext_vector_type(8)));
typedef float f32x4 __attribute__((ext_vector_type(4)));

#define LDT 72
#define HLD 516

// ---------- bf16 helpers ----------
__device__ __forceinline__ float bf2f(u16 u) {
  u32 v = ((u32)u) << 16;
  return __builtin_bit_cast(float, v);
}
__device__ __forceinline__ u16 f2bf(float f) {
  u32 u = __builtin_bit_cast(u32, f);
  u32 r = u + 0x7fffu + ((u >> 16) & 1u);
  return (u16)(r >> 16);
}

__device__ __forceinline__ float block_sum4(float v, float* red, int t) {
#pragma unroll
  for (int o = 32; o; o >>= 1) v += __shfl_xor(v, o, 64);
  if ((t & 63) == 0) red[t >> 6] = v;
  __syncthreads();
  float r = red[0] + red[1] + red[2] + red[3];
  __syncthreads();
  return r;
}

// async global->LDS, 16B per lane
#define GLD16(gp, lp)                                                   \
  __builtin_amdgcn_global_load_lds(                                     \
      (const __attribute__((address_space(1))) void*)(gp),              \
      (__attribute__((address_space(3))) void*)(lp), 16, 0, 0)

// ---- kernel 1: blocks [0,1024) convert Wv fp32->bf16; rest do LN1 rows -----
__global__ __launch_bounds__(256) void cvt_ln(
    const float* __restrict__ WV, u16* __restrict__ WVD,
    const float* __restrict__ X, const float* __restrict__ G,
    const float* __restrict__ Bt, u16* __restrict__ O) {
  int t = threadIdx.x;
  if (blockIdx.x < 1024) {
    int i = blockIdx.x * 1024 + t * 4;
    float4 f = *(const float4*)(WV + i);
    u32 lo = (u32)f2bf(f.x) | ((u32)f2bf(f.y) << 16);
    u32 hi = (u32)f2bf(f.z) | ((u32)f2bf(f.w) << 16);
    uint2 val = {lo, hi};
    *(uint2*)(WVD + i) = val;
    return;
  }
  __shared__ float red[4];
  int row = blockIdx.x - 1024;
  float4 xv = *(const float4*)(X + (size_t)row * 1024 + t * 4);
  float v[4] = {xv.x, xv.y, xv.z, xv.w};
  float s = v[0] + v[1] + v[2] + v[3];
  s = block_sum4(s, red, t);
  float mean = s * (1.f / 1024.f);
  float q = 0.f;
#pragma unroll
  for (int i = 0; i < 4; ++i) { float d = v[i] - mean; q += d * d; }
  q = block_sum4(q, red, t);
  float rstd = rsqrtf(q * (1.f / 1024.f) + 1e-5f);
  float4 g = *(const float4*)(G + t * 4);
  float4 b = *(const float4*)(Bt + t * 4);
  float gg[4] = {g.x, g.y, g.z, g.w}, bb[4] = {b.x, b.y, b.z, b.w};
  u16 o[4];
#pragma unroll
  for (int i = 0; i < 4; ++i) o[i] = f2bf((v[i] - mean) * rstd * gg[i] + bb[i]);
  u32* op = (u32*)(O + (size_t)row * 1024 + t * 4);
  op[0] = (u32)o[0] | ((u32)o[1] << 16);
  op[1] = (u32)o[2] | ((u32)o[3] << 16);
}

// ---- kernel 2: [0,592) = 128x64-tile v-GEMM (GLD16 + XOR swizzle, 2.3
// ---- blocks/CU for latency overlap); [592,720) = q_fused -------------------
__global__ __launch_bounds__(256) void vgemm_q(
    const u16* __restrict__ A, const u16* __restrict__ W,
    const float* __restrict__ bias, u16* __restrict__ C, int M,
    const float* __restrict__ WQ, const float* __restrict__ QB,
    const float* __restrict__ WK, const float* __restrict__ BK,
    u16* __restrict__ QW, float* __restrict__ C0) {
  int t = threadIdx.x;
  if (blockIdx.x < 592) {
    __shared__ u16 As[128 * 64];
    __shared__ u16 Bs[64 * 64];
    int lane = t & 63, wv = t >> 6;
    int bm = (blockIdx.x % 37) * 128, bn = (blockIdx.x / 37) * 64;
    int quad = lane >> 4, rlow = lane & 15;
    int lrow = lane >> 3;                    // 0..7 = row within 8-row block
    int lcol = (((lane & 7) ^ lrow) * 8);    // XOR-swizzled global chunk
    int wrow = (wv & 1) * 64, wcol = (wv >> 1) * 32;
    int rx = (rlow & 7) << 3;                // swizzle term for reads (u16)
    f32x4 acc[4][2] = {};
    for (int k0 = 0; k0 < 1024; k0 += 64) {
      __syncthreads();
#pragma unroll
      for (int j = 0; j < 4; ++j) {          // A: 16 row-blocks of 8 rows
        int rb = j * 4 + wv;
        int row = rb * 8 + lrow;
        int gm = bm + row; if (gm >= M) gm = M - 1;  // clamp: dup, never stored
        GLD16(A + (size_t)gm * 1024 + k0 + lcol, &As[rb * 8 * 64]);
      }
#pragma unroll
      for (int j = 0; j < 2; ++j) {          // B: 8 row-blocks of 8 rows
        int rb = j * 4 + wv;
        int gn = bn + rb * 8 + lrow;         // N = 1024 exact
        GLD16(W + (size_t)gn * 1024 + k0 + lcol, &Bs[rb * 8 * 64]);
      }
      __syncthreads();
#pragma unroll
      for (int kk = 0; kk < 64; kk += 32) {
        int coff = ((kk >> 3) + quad) << 3;  // cq*8 u16
        bf16x8 a[4], b[2];
#pragma unroll
        for (int i = 0; i < 4; ++i)
          a[i] = *(const bf16x8*)(&As[(wrow + i * 16 + rlow) * 64 + (coff ^ rx)]);
#pragma unroll
        for (int j = 0; j < 2; ++j)
          b[j] = *(const bf16x8*)(&Bs[(wcol + j * 16 + rlow) * 64 + (coff ^ rx)]);
#pragma unroll
        for (int i = 0; i < 4; ++i)
#pragma unroll
          for (int j = 0; j < 2; ++j)
            acc[i][j] = __builtin_amdgcn_mfma_f32_16x16x32_bf16(a[i], b[j], acc[i][j], 0, 0, 0);
      }
    }
#pragma unroll
    for (int j = 0; j < 2; ++j) {
      int gn = bn + wcol + j * 16 + rlow;
      float bv = bias[gn];
#pragma unroll
      for (int i = 0; i < 4; ++i)
#pragma unroll
        for (int r = 0; r < 4; ++r) {
          int gm = bm + wrow + i * 16 + quad * 4 + r;
          if (gm < M) C[(size_t)gm * 1024 + gn] = f2bf(acc[i][j][r] + bv);
        }
    }
    return;
  }
  // ----- q_fused segment -----
  __shared__ float hsf[1024];
  __shared__ float ps[256];
  __shared__ float qs[64];
  int bh = blockIdx.x - 592, b = bh >> 4, h = bh & 15;
  {
    uint2 two = *(const uint2*)(A + (size_t)b * 1024 + t * 4);
    hsf[t * 4 + 0] = bf2f(two.x & 0xffff);
    hsf[t * 4 + 1] = bf2f(two.x >> 16);
    hsf[t * 4 + 2] = bf2f(two.y & 0xffff);
    hsf[t * 4 + 3] = bf2f(two.y >> 16);
  }
  __syncthreads();
  {
    int n = t >> 2, part = t & 3;
    const float* wr = WQ + (size_t)(h * 64 + n) * 1024 + part * 256;
    const float* hp = hsf + part * 256;
    float acc = 0.f;
#pragma unroll 4
    for (int d = 0; d < 256; d += 4) {
      float4 w = *(const float4*)(wr + d);
      acc += w.x * hp[d] + w.y * hp[d + 1] + w.z * hp[d + 2] + w.w * hp[d + 3];
    }
    ps[t] = acc;
  }
  __syncthreads();
  if (t < 64) {
    float q = ps[t * 4] + ps[t * 4 + 1] + ps[t * 4 + 2] + ps[t * 4 + 3] + QB[h * 64 + t];
    qs[t] = q * 0.125f;
  }
  __syncthreads();
  float a4[4] = {0.f, 0.f, 0.f, 0.f};
  int d0 = t * 4;
#pragma unroll 4
  for (int n2 = 0; n2 < 64; ++n2) {
    float4 w = *(const float4*)(WK + (size_t)(h * 64 + n2) * 1024 + d0);
    float q = qs[n2];
    a4[0] += q * w.x; a4[1] += q * w.y; a4[2] += q * w.z; a4[3] += q * w.w;
  }
  u16 o[4];
#pragma unroll
  for (int i = 0; i < 4; ++i) o[i] = f2bf(a4[i]);
  u32* op = (u32*)(QW + (size_t)bh * 1024 + d0);
  op[0] = (u32)o[0] | ((u32)o[1] << 16);
  op[1] = (u32)o[2] | ((u32)o[3] << 16);
  if (t == 0) {
    float c = 0.f;
    for (int n2 = 0; n2 < 64; ++n2) c += qs[n2] * BK[h * 64 + n2];
    C0[bh] = c;
  }
}

// ---- split-K partials, W in fp32 (converted during staging) ----------------
__global__ __launch_bounds__(256) void gemm_bt_splitk_p(
    const u16* __restrict__ A, int lda, const float* __restrict__ Wf, int ldw,
    float* __restrict__ P, int pstride, int ldc, int M, int N, int KC) {
  __shared__ u16 As[64 * LDT];
  __shared__ u16 Bs[64 * LDT];
  int t = threadIdx.x;
  int bm = blockIdx.x * 64, bn = blockIdx.y * 64;
  int kbase = blockIdx.z * KC;
  float* PZ = P + (size_t)blockIdx.z * pstride;
  int lane = t & 63, wv = t >> 6;
  f32x4 acc[4] = {};
  int srow = t >> 3, scol = (t & 7) * 8;

  for (int k0 = kbase; k0 < kbase + KC; k0 += 64) {
    __syncthreads();
#pragma unroll
    for (int rr = 0; rr < 2; ++rr) {
      int r = srow + rr * 32;
      int gm = bm + r;
      uint4 da = {0, 0, 0, 0};
      if (gm < M) da = *(const uint4*)(A + (size_t)gm * lda + k0 + scol);
      *(uint4*)(&As[r * LDT + scol]) = da;
      int gn = bn + r;
      uint4 dw = {0, 0, 0, 0};
      if (gn < N) {
        const float* wr = Wf + (size_t)gn * ldw + k0 + scol;
        float4 w0 = *(const float4*)(wr);
        float4 w1 = *(const float4*)(wr + 4);
        dw.x = (u32)f2bf(w0.x) | ((u32)f2bf(w0.y) << 16);
        dw.y = (u32)f2bf(w0.z) | ((u32)f2bf(w0.w) << 16);
        dw.z = (u32)f2bf(w1.x) | ((u32)f2bf(w1.y) << 16);
        dw.w = (u32)f2bf(w1.z) | ((u32)f2bf(w1.w) << 16);
      }
      *(uint4*)(&Bs[r * LDT + scol]) = dw;
    }
    __syncthreads();
    int quad = lane >> 4, rlow = lane & 15;
#pragma unroll
    for (int kk = 0; kk < 64; kk += 32) {
      bf16x8 a = *(const bf16x8*)(&As[(wv * 16 + rlow) * LDT + kk + quad * 8]);
#pragma unroll
      for (int j = 0; j < 4; ++j) {
        bf16x8 b = *(const bf16x8*)(&Bs[(j * 16 + rlow) * LDT + kk + quad * 8]);
        acc[j] = __builtin_amdgcn_mfma_f32_16x16x32_bf16(a, b, acc[j], 0, 0, 0);
      }
    }
  }
  int quad = lane >> 4, cidx = lane & 15;
#pragma unroll
  for (int j = 0; j < 4; ++j) {
    int gn = bn + j * 16 + cidx;
#pragma unroll
    for (int r = 0; r < 4; ++r) {
      int gm = bm + wv * 16 + quad * 4 + r;
      if (gm < M && gn < N) PZ[(size_t)gm * ldc + gn] = acc[j][r];
    }
  }
}

// ---- reduce 8 out-proj partials(+bias) + x0 residual + LN2 ------------------
__global__ __launch_bounds__(256) void resid_ln_red(
    const float* __restrict__ X, const float* __restrict__ OP,
    const float* __restrict__ OB, const float* __restrict__ G,
    const float* __restrict__ Bt, float* __restrict__ CLS, u16* __restrict__ H2) {
  __shared__ float red[4];
  const int PS = 136 * 1024;
  int row = blockIdx.x, t = threadIdx.x;
  int bi = (row < 128) ? (row >> 4) : (row - 128);
  float4 xv = *(const float4*)(X + (size_t)bi * 1024 + t * 4);
  float4 ob = *(const float4*)(OB + t * 4);
  float v[4] = {xv.x + ob.x, xv.y + ob.y, xv.z + ob.z, xv.w + ob.w};
#pragma unroll
  for (int z = 0; z < 8; ++z) {
    float4 pv = *(const float4*)(OP + (size_t)z * PS + (size_t)row * 1024 + t * 4);
    v[0] += pv.x; v[1] += pv.y; v[2] += pv.z; v[3] += pv.w;
  }
  float* cp = CLS + (size_t)row * 1024 + t * 4;
#pragma unroll
  for (int i = 0; i < 4; ++i) cp[i] = v[i];
  float s = v[0] + v[1] + v[2] + v[3];
  s = block_sum4(s, red, t);
  float mean = s * (1.f / 1024.f);
  float q = 0.f;
#pragma unroll
  for (int i = 0; i < 4; ++i) { float d = v[i] - mean; q += d * d; }
  q = block_sum4(q, red, t);
  float rstd = rsqrtf(q * (1.f / 1024.f) + 1e-5f);
  float4 g = *(const float4*)(G + t * 4);
  float4 b = *(const float4*)(Bt + t * 4);
  float gg[4] = {g.x, g.y, g.z, g.w}, bb[4] = {b.x, b.y, b.z, b.w};
  u16 o[4];
#pragma unroll
  for (int i = 0; i < 4; ++i) o[i] = f2bf((v[i] - mean) * rstd * gg[i] + bb[i]);
  u32* op = (u32*)(H2 + (size_t)row * 1024 + t * 4);
  op[0] = (u32)o[0] | ((u32)o[1] << 16);
  op[1] = (u32)o[2] | ((u32)o[3] << 16);
}

// ---- reduce 4 fc partials + bias, QuickGELU -> bf16 ------------------------
__global__ __launch_bounds__(256) void gelu_red(
    const float* __restrict__ FP, const float* __restrict__ FB,
    u16* __restrict__ O, int total) {
  const int PS = 136 * 4096;
  int i = (blockIdx.x * 256 + threadIdx.x) * 4;
  if (i < total) {
#pragma unroll
    for (int k = 0; k < 4; ++k) {
      int idx = i + k;
      float v = FB[idx & 4095];
#pragma unroll
      for (int z = 0; z < 4; ++z) v += FP[(size_t)z * PS + idx];
      O[idx] = f2bf(v / (1.f + __expf(-1.702f * v)));
    }
  }
}

// ---- reduce 16 proj partials + bias + clspre -> fp32 out -------------------
__global__ __launch_bounds__(256) void final_red(
    const float* __restrict__ PP, const float* __restrict__ PB,
    const float* __restrict__ CLS, float* __restrict__ O, int total) {
  const int PS = 136 * 1024;
  int i = (blockIdx.x * 256 + threadIdx.x) * 4;
  if (i < total) {
#pragma unroll
    for (int k = 0; k < 4; ++k) {
      int idx = i + k;
      float v = PB[idx & 1023] + CLS[idx];
#pragma unroll
      for (int z = 0; z < 16; ++z) v += PP[(size_t)z * PS + idx];
      O[idx] = v;
    }
  }
}

// ------ attn: h-tile AND qw rows staged in LDS; 4 independent accs ----------
__global__ __launch_bounds__(256) void attn_dot(
    const u16* __restrict__ H, const u16* __restrict__ QW,
    const float* __restrict__ C0, float* __restrict__ ATT) {
  __shared__ __align__(16) u32 Hs[16 * HLD];
  __shared__ __align__(16) u32 Qs[16 * HLD];
  int b = blockIdx.y, s0 = blockIdx.x * 16, t = threadIdx.x;
  for (int idx = t; idx < 16 * 512; idx += 256) {
    int row = idx >> 9, col = idx & 511;
    int s = s0 + row;
    u32 v = 0;
    if (s < 577) v = *(const u32*)(H + ((size_t)(s * 8 + b) << 10) + col * 2);
    Hs[row * HLD + col] = v;
    Qs[row * HLD + col] = *(const u32*)(QW + (size_t)(b * 16 + row) * 1024 + col * 2);
  }
  __syncthreads();
  int si = t & 15, hh = t >> 4;
  int s = s0 + si;
  if (s < 577) {
    const u32* hr = &Hs[si * HLD];
    const u32* qr = &Qs[hh * HLD];
    float a0 = 0.f, a1 = 0.f, a2 = 0.f, a3 = 0.f;
    for (int d = 0; d < 512; d += 8) {
      uint4 hv = *(const uint4*)(&hr[d]);
      uint4 qv = *(const uint4*)(&qr[d]);
      uint4 hw = *(const uint4*)(&hr[d + 4]);
      uint4 qw2 = *(const uint4*)(&qr[d + 4]);
      a0 += bf2f(hv.x & 0xffff) * bf2f(qv.x & 0xffff) + bf2f(hv.x >> 16) * bf2f(qv.x >> 16);
      a1 += bf2f(hv.y & 0xffff) * bf2f(qv.y & 0xffff) + bf2f(hv.y >> 16) * bf2f(qv.y >> 16);
      a2 += bf2f(hv.z & 0xffff) * bf2f(qv.z & 0xffff) + bf2f(hv.z >> 16) * bf2f(qv.z >> 16);
      a3 += bf2f(hv.w & 0xffff) * bf2f(qv.w & 0xffff) + bf2f(hv.w >> 16) * bf2f(qv.w >> 16);
      a0 += bf2f(hw.x & 0xffff) * bf2f(qw2.x & 0xffff) + bf2f(hw.x >> 16) * bf2f(qw2.x >> 16);
      a1 += bf2f(hw.y & 0xffff) * bf2f(qw2.y & 0xffff) + bf2f(hw.y >> 16) * bf2f(qw2.y >> 16);
      a2 += bf2f(hw.z & 0xffff) * bf2f(qw2.z & 0xffff) + bf2f(hw.z >> 16) * bf2f(qw2.z >> 16);
      a3 += bf2f(hw.w & 0xffff) * bf2f(qw2.w & 0xffff) + bf2f(hw.w >> 16) * bf2f(qw2.w >> 16);
    }
    ATT[(size_t)(b * 16 + hh) * 577 + s] = (a0 + a1) + (a2 + a3) + C0[b * 16 + hh];
  }
}

// ---- softmax(attn [+mask fp32]) then PV over bf16 V ------------------------
__global__ __launch_bounds__(256) void softmax_pv(
    const float* __restrict__ ATT, const float* __restrict__ MASK,
    const u16* __restrict__ V, u16* __restrict__ AO) {
  const int S = 577;
  int blk = blockIdx.x;
  int b = blk / 272, rem = blk % 272;
  int x = rem >> 4, h = rem & 15;
  __shared__ float p[S];
  __shared__ float redm[4];
  __shared__ float reds[4];
  __shared__ float partial[256];
  int t = threadIdx.x, lane = t & 63, wv = t >> 6;
  const float* arow = ATT + (size_t)(b * 16 + h) * S;
  float lmax = -3e38f;
  for (int s = t; s < S; s += 256) {
    float v = arow[s];
    if (x < 16) v += MASK[(size_t)((b * 16 + x) * 16 + h) * S + s];
    p[s] = v;
    lmax = fmaxf(lmax, v);
  }
#pragma unroll
  for (int o = 32; o; o >>= 1) lmax = fmaxf(lmax, __shfl_xor(lmax, o, 64));
  if (lane == 0) redm[wv] = lmax;
  __syncthreads();
  float m = fmaxf(fmaxf(redm[0], redm[1]), fmaxf(redm[2], redm[3]));
  float lsum = 0.f;
  for (int s = t; s < S; s += 256) {
    float e = __expf(p[s] - m);
    p[s] = e;
    lsum += e;
  }
#pragma unroll
  for (int o = 32; o; o >>= 1) lsum += __shfl_xor(lsum, o, 64);
  if (lane == 0) reds[wv] = lsum;
  __syncthreads();
  float inv = 1.f / (reds[0] + reds[1] + reds[2] + reds[3]);
  float acc = 0.f;
  const u16* vb = V + h * 64 + lane;
  int s = wv;
  for (; s + 28 < S; s += 32) {
    float w0 = p[s], w1 = p[s + 4], w2 = p[s + 8], w3 = p[s + 12];
    float w4 = p[s + 16], w5 = p[s + 20], w6 = p[s + 24], w7 = p[s + 28];
    float v0 = bf2f(vb[(size_t)((s)*8 + b) << 10]);
    float v1 = bf2f(vb[(size_t)((s + 4) * 8 + b) << 10]);
    float v2 = bf2f(vb[(size_t)((s + 8) * 8 + b) << 10]);
    float v3 = bf2f(vb[(size_t)((s + 12) * 8 + b) << 10]);
    float v4 = bf2f(vb[(size_t)((s + 16) * 8 + b) << 10]);
    float v5 = bf2f(vb[(size_t)((s + 20) * 8 + b) << 10]);
    float v6 = bf2f(vb[(size_t)((s + 24) * 8 + b) << 10]);
    float v7 = bf2f(vb[(size_t)((s + 28) * 8 + b) << 10]);
    acc += w0 * v0 + w1 * v1 + w2 * v2 + w3 * v3;
    acc += w4 * v4 + w5 * v5 + w6 * v6 + w7 * v7;
  }
  for (; s < S; s += 4) acc += p[s] * bf2f(vb[(size_t)(s * 8 + b) << 10]);
  partial[t] = acc;
  __syncthreads();
  if (t < 64) {
    float r = (partial[t] + partial[t + 64] + partial[t + 128] + partial[t + 192]) * inv;
    int row = (x < 16) ? (b * 16 + x) : (128 + b);
    AO[(size_t)row * 1024 + h * 64 + t] = f2bf(r);
  }
}

// ----------------------------------------------------------------------------
extern "C" void kernel_launch(void* const* d_in, const int* in_sizes, int n_in,
                              void* d_out, int out_size, void* d_ws, size_t ws_size,
                              hipStream_t stream) {
  const float* x      = (const float*)d_in[0];
  const float* mask   = (const float*)d_in[1];
  const float* in_w   = (const float*)d_in[5];
  const float* in_b   = (const float*)d_in[6];
  const float* out_w  = (const float*)d_in[7];
  const float* out_b  = (const float*)d_in[8];
  const float* ln1_g  = (const float*)d_in[9];
  const float* ln1_b  = (const float*)d_in[10];
  const float* ln2_g  = (const float*)d_in[11];
  const float* ln2_b  = (const float*)d_in[12];
  const float* fc_w   = (const float*)d_in[13];
  const float* fc_b   = (const float*)d_in[14];
  const float* proj_w = (const float*)d_in[15];
  const float* proj_b = (const float*)d_in[16];
  float* out = (float*)d_out;

  const int SB = 577 * 8;  // 4616
  char* base = (char*)d_ws;
  size_t off = 0;
  auto alloc = [&](size_t bytes) {
    char* p = base + off;
    off += (bytes + 255) & ~(size_t)255;
    return p;
  };
  u16* wv_b     = (u16*)alloc((size_t)1024 * 1024 * 2);
  u16* h        = (u16*)alloc((size_t)SB * 1024 * 2);
  u16* v        = (u16*)alloc((size_t)SB * 1024 * 2);
  u16* qw       = (u16*)alloc(128 * 1024 * 2);
  float* c0     = (float*)alloc(128 * 4);
  float* attn   = (float*)alloc(128 * 577 * 4);
  u16* attn_out = (u16*)alloc(136 * 1024 * 2);
  float* Op     = (float*)alloc((size_t)8 * 136 * 1024 * 4);
  float* clspre = (float*)alloc(136 * 1024 * 4);
  u16* h2       = (u16*)alloc(136 * 1024 * 2);
  float* Fp     = (float*)alloc((size_t)4 * 136 * 4096 * 4);
  u16* hg       = (u16*)alloc((size_t)136 * 4096 * 2);
  float* Pp     = (float*)alloc((size_t)16 * 136 * 1024 * 4);
  // ~46 MB used; ws_size ~268 MB (measured R7)

  // 1) wv cvt + LN1 fused
  cvt_ln<<<1024 + SB, 256, 0, stream>>>(in_w + (size_t)2048 * 1024, wv_b,
                                        x, ln1_g, ln1_b, h);
  // 2) v-GEMM (128x64 tiles, 592 blocks for 2.3/CU occupancy) + q_fused
  vgemm_q<<<592 + 128, 256, 0, stream>>>(
      h, wv_b, in_b + 2048, v, SB,
      in_w, in_b, in_w + (size_t)1024 * 1024, in_b + 1024, qw, c0);
  // 3) attn logits
  attn_dot<<<dim3(37, 8), 256, 0, stream>>>(h, qw, c0, attn);
  // 4) softmax(+mask) + PV
  softmax_pv<<<8 * 17 * 16, 256, 0, stream>>>(attn, mask, v, attn_out);
  // 5) out-proj partials (z=8, KC=128), fp32 W
  gemm_bt_splitk_p<<<dim3(3, 16, 8), 256, 0, stream>>>(
      attn_out, 1024, out_w, 1024, Op, 136 * 1024, 1024, 136, 1024, 128);
  // 6) reduce(8) + residual + LN2
  resid_ln_red<<<136, 256, 0, stream>>>(x, Op, out_b, ln2_g, ln2_b, clspre, h2);
  // 7) fc partials (z=4, KC=256), fp32 W; then reduce+bias+QuickGELU
  gemm_bt_splitk_p<<<dim3(3, 64, 4), 256, 0, stream>>>(
      h2, 1024, fc_w, 1024, Fp, 136 * 4096, 4096, 136, 4096, 256);
  gelu_red<<<544, 256, 0, stream>>>(Fp, fc_b, hg, 136 * 4096);
  // 8) proj partials (z=16, KC=256), fp32 W; then reduce+bias+clspre -> out
  gemm_bt_splitk_p<<<dim3(3, 16, 16), 256, 0, stream>>>(
      hg, 4096, proj_w, 4096, Pp, 136 * 1024, 1024, 136, 1024, 256);
  final_red<<<136, 256, 0, stream>>>(Pp, proj_b, clspre, out, 136 * 1024);

  (void)in_sizes; (void)n_in; (void)out_size; (void)ws_size;
}